// Round 6
// baseline (61.737 us; speedup 1.0000x reference)
//
#include <hip/hip_runtime.h>

#define Bq 8
#define Tq 4096
#define Dq 1024
#define NLEAF 8      // valid leaves (nodes 7..14)
#define SUBSEQ 256   // timesteps per leaf
#define TSPLIT 8     // partial splits per leaf (512 blocks total)
#define NNODES 15
#define ROWS_PER_WAVE 4

typedef float f32x4 __attribute__((ext_vector_type(4)));

// Kernel 1: partial leaf sums. grid = (B*NLEAF, TSPLIT), block = 256 (float4 over D).
__global__ __launch_bounds__(256) void k_leaf_partial(const float* __restrict__ x,
                                                      float* __restrict__ partial) {
    const int bl = blockIdx.x;          // b*8 + l
    const int p  = blockIdx.y;          // 0..7
    const int q  = threadIdx.x;         // float4 index over D (0..255)
    const int b = bl >> 3, l = bl & 7;
    const float4* xp = (const float4*)(x + ((size_t)b * Tq + (size_t)l * SUBSEQ + (size_t)p * (SUBSEQ / TSPLIT)) * Dq) + q;
    float4 s = {0.f, 0.f, 0.f, 0.f};
#pragma unroll 8
    for (int t = 0; t < SUBSEQ / TSPLIT; ++t) {
        float4 xv = xp[(size_t)t * (Dq / 4)];
        s.x += xv.x; s.y += xv.y; s.z += xv.z; s.w += xv.w;
    }
    ((float4*)partial)[((size_t)bl * TSPLIT + p) * (Dq / 4) + q] = s;
}

// Kernel 2: softmax over node_weights + mixture. grid = B, block = 1024 (one thread per d).
__global__ __launch_bounds__(1024) void k_mixture(const float* __restrict__ partial,
                                                  const float* __restrict__ nw,
                                                  float* __restrict__ mixture) {
    const int b = blockIdx.x;
    const int d = threadIdx.x;
    float v[NNODES];
    float m = -1e30f;
#pragma unroll
    for (int n = 0; n < NNODES; ++n) {
        v[n] = nw[n * Dq + d];
        m = fmaxf(m, v[n]);
    }
    float denom = 0.f;
#pragma unroll
    for (int n = 0; n < NNODES; ++n) {
        v[n] = expf(v[n] - m);
        denom += v[n];
    }
    const float inv_denom = 1.0f / denom;
    float acc = 0.f;
#pragma unroll
    for (int l = 0; l < NLEAF; ++l) {
        float s = 0.f;
#pragma unroll
        for (int p = 0; p < TSPLIT; ++p)
            s += partial[(((size_t)(b * NLEAF + l)) * TSPLIT + p) * Dq + d];
        acc += (v[7 + l] * inv_denom) * (s * (1.0f / (float)SUBSEQ));
    }
    mixture[b * Dq + d] = acc;
}

// Kernel 3: out[b,t,:] = LN(x[b,t,:] + mixture[b,:]) * gamma + beta.
// Wave handles ROWS_PER_WAVE consecutive rows; mixture/gamma/beta hoisted into
// registers once per wave (they are row-invariant; all rows of a wave share b
// since 16 | 4096). Cuts per-row L2 traffic 4x. No LDS, no barriers, NT stores.
// Block = 256 (4 waves), grid = B*T / (4*ROWS_PER_WAVE) = 2048.
__global__ __launch_bounds__(256) void k_ln(const float* __restrict__ x,
                                            const float* __restrict__ mixture,
                                            const float* __restrict__ gamma,
                                            const float* __restrict__ beta,
                                            float* __restrict__ out) {
    const int wid  = threadIdx.x >> 6;
    const int lane = threadIdx.x & 63;
    const int row0 = (blockIdx.x * 4 + wid) * ROWS_PER_WAVE;   // b*T + t
    const int b    = row0 >> 12;              // T = 4096
    const float4* mr = (const float4*)(mixture + (size_t)b * Dq);
    float4 mv[4], gv[4], bv[4];
#pragma unroll
    for (int k = 0; k < 4; ++k) {
        mv[k] = mr[lane + 64 * k];
        gv[k] = ((const float4*)gamma)[lane + 64 * k];
        bv[k] = ((const float4*)beta)[lane + 64 * k];
    }
#pragma unroll 2
    for (int r = 0; r < ROWS_PER_WAVE; ++r) {
        const size_t row = (size_t)row0 + r;
        const float4* xr = (const float4*)(x + row * Dq);
        float4 o[4];
        float sum = 0.f, sq = 0.f;
#pragma unroll
        for (int k = 0; k < 4; ++k) {
            const float4 xv = xr[lane + 64 * k];
            o[k].x = xv.x + mv[k].x;
            o[k].y = xv.y + mv[k].y;
            o[k].z = xv.z + mv[k].z;
            o[k].w = xv.w + mv[k].w;
            sum += o[k].x + o[k].y + o[k].z + o[k].w;
            sq  += o[k].x * o[k].x + o[k].y * o[k].y + o[k].z * o[k].z + o[k].w * o[k].w;
        }
#pragma unroll
        for (int i = 32; i >= 1; i >>= 1) {
            sum += __shfl_xor(sum, i, 64);
            sq  += __shfl_xor(sq, i, 64);
        }
        const float mu   = sum * (1.0f / 1024.0f);
        const float var  = sq * (1.0f / 1024.0f) - mu * mu;
        const float rstd = rsqrtf(var + 1e-5f);
        f32x4* orow = (f32x4*)(out + row * Dq);
#pragma unroll
        for (int k = 0; k < 4; ++k) {
            f32x4 rr;
            rr.x = (o[k].x - mu) * rstd * gv[k].x + bv[k].x;
            rr.y = (o[k].y - mu) * rstd * gv[k].y + bv[k].y;
            rr.z = (o[k].z - mu) * rstd * gv[k].z + bv[k].z;
            rr.w = (o[k].w - mu) * rstd * gv[k].w + bv[k].w;
            __builtin_nontemporal_store(rr, &orow[lane + 64 * k]);
        }
    }
}

extern "C" void kernel_launch(void* const* d_in, const int* in_sizes, int n_in,
                              void* d_out, int out_size, void* d_ws, size_t ws_size,
                              hipStream_t stream) {
    const float* x     = (const float*)d_in[0];
    // d_in[1] = W_proj, d_in[2] = threshold: numerically dead (all gated states are exactly 0)
    const float* nw    = (const float*)d_in[3];
    const float* gamma = (const float*)d_in[4];
    const float* beta  = (const float*)d_in[5];
    float* out = (float*)d_out;

    float* partial = (float*)d_ws;                               // 8*8*8*1024 floats = 2 MiB
    float* mixture = partial + (size_t)Bq * NLEAF * TSPLIT * Dq; // 8*1024 floats

    k_leaf_partial<<<dim3(Bq * NLEAF, TSPLIT), 256, 0, stream>>>(x, partial);
    k_mixture<<<Bq, 1024, 0, stream>>>(partial, nw, mixture);
    k_ln<<<Bq * Tq / (4 * ROWS_PER_WAVE), 256, 0, stream>>>(x, mixture, gamma, beta, out);
}

// Round 8
// 59.406 us; speedup vs baseline: 1.0392x; 1.0392x over previous
//
#include <hip/hip_runtime.h>
#include <hip/hip_cooperative_groups.h>

namespace cg = cooperative_groups;

#define Bq 8
#define Tq 4096
#define Dq 1024
#define HALF 2048      // first-half timesteps per batch (leaf region)
#define NNODES 15
#define SUBSEQ 256
#define TSPLIT 8
#define CGRID 512      // cooperative grid: needs only 2 blocks/CU co-resident
#define CBLOCK 512     // 8 waves/block

typedef float f32x4 __attribute__((ext_vector_type(4)));

// ---------------- fused cooperative kernel ----------------
// Phase 1 : each wave reads 4 first-half rows (HELD in registers, 64 VGPR),
//           block reduces 8 waves' sums -> partial[blk][0..1023].
// Phase 2a: blocks 0..15 compute mixture[b,d] from partials + softmax(nw).
// Phase 2b: LN the 4 held rows (zero re-read) + 4 fresh second-half rows/wave.
__global__ __launch_bounds__(CBLOCK, 4) void k_fused(
    const float* __restrict__ x, const float* __restrict__ nw,
    const float* __restrict__ gamma, const float* __restrict__ beta,
    float* __restrict__ partial, float* __restrict__ mixture,
    float* __restrict__ out)
{
    const int tid  = threadIdx.x;
    const int wid  = tid >> 6;            // 0..7
    const int lane = tid & 63;
    const int blk  = blockIdx.x;
    const int fbase = blk * 32 + wid * 4; // flat first-half row = b*2048 + t
    const int b  = fbase >> 11;
    const int t0 = fbase & 2047;

    // ---- Phase 1 ----
    const float4* xr = (const float4*)(x + ((size_t)b * Tq + t0) * Dq);
    float4 h[4][4];
    float4 s[4] = {{0,0,0,0},{0,0,0,0},{0,0,0,0},{0,0,0,0}};
#pragma unroll
    for (int r = 0; r < 4; ++r)
#pragma unroll
        for (int k = 0; k < 4; ++k) {
            h[r][k] = xr[(size_t)r * 256 + lane + 64 * k];
            s[k].x += h[r][k].x; s[k].y += h[r][k].y;
            s[k].z += h[r][k].z; s[k].w += h[r][k].w;
        }
    __shared__ float4 ldsv[8][256];
#pragma unroll
    for (int k = 0; k < 4; ++k) ldsv[wid][lane + 64 * k] = s[k];
    __syncthreads();
    if (tid < 256) {
        float4 a = ldsv[0][tid];
#pragma unroll
        for (int w = 1; w < 8; ++w) {
            a.x += ldsv[w][tid].x; a.y += ldsv[w][tid].y;
            a.z += ldsv[w][tid].z; a.w += ldsv[w][tid].w;
        }
        ((float4*)partial)[(size_t)blk * 256 + tid] = a;   // partial[blk][:]
    }
    cg::this_grid().sync();

    // ---- Phase 2a: 16 blocks x 512 threads = 8192 (b,d) pairs ----
    if (blk < 16) {
        const int b2 = blk >> 1;
        const int d  = ((blk & 1) << 9) + tid;
        float v[NNODES];
        float m = -1e30f;
#pragma unroll
        for (int n = 0; n < NNODES; ++n) {
            v[n] = nw[n * Dq + d];
            m = fmaxf(m, v[n]);
        }
        float denom = 0.f;
#pragma unroll
        for (int n = 0; n < NNODES; ++n) {
            v[n] = expf(v[n] - m);
            denom += v[n];
        }
        const float inv_denom = 1.0f / denom;
        float acc = 0.f;
#pragma unroll
        for (int l = 0; l < 8; ++l) {
            float ls = 0.f;
#pragma unroll
            for (int j = 0; j < 8; ++j)   // leaf l = 8 blocks of 32 rows
                ls += partial[(size_t)((b2 * 64 + l * 8 + j) << 10) + d];
            acc += (v[7 + l] * inv_denom) * (ls * (1.0f / 256.0f));
        }
        mixture[b2 * Dq + d] = acc;
    }
    cg::this_grid().sync();

    // ---- Phase 2b ----
    const float4* mr = (const float4*)(mixture + (size_t)b * Dq);
    const float4* gp = (const float4*)gamma;
    const float4* bp = (const float4*)beta;

#pragma unroll
    for (int r = 0; r < 4; ++r) {          // held rows: no x re-read
        float4 o[4];
        float sum = 0.f, sq = 0.f;
#pragma unroll
        for (int k = 0; k < 4; ++k) {
            const float4 mv = mr[lane + 64 * k];
            o[k].x = h[r][k].x + mv.x;
            o[k].y = h[r][k].y + mv.y;
            o[k].z = h[r][k].z + mv.z;
            o[k].w = h[r][k].w + mv.w;
            sum += o[k].x + o[k].y + o[k].z + o[k].w;
            sq  += o[k].x * o[k].x + o[k].y * o[k].y + o[k].z * o[k].z + o[k].w * o[k].w;
        }
#pragma unroll
        for (int i = 32; i >= 1; i >>= 1) {
            sum += __shfl_xor(sum, i, 64);
            sq  += __shfl_xor(sq, i, 64);
        }
        const float mu   = sum * (1.0f / 1024.0f);
        const float var  = sq * (1.0f / 1024.0f) - mu * mu;
        const float rstd = rsqrtf(var + 1e-5f);
        f32x4* orow = (f32x4*)(out + ((size_t)b * Tq + t0 + r) * Dq);
#pragma unroll
        for (int k = 0; k < 4; ++k) {
            const float4 gv = gp[lane + 64 * k];
            const float4 bv = bp[lane + 64 * k];
            f32x4 rr;
            rr.x = (o[k].x - mu) * rstd * gv.x + bv.x;
            rr.y = (o[k].y - mu) * rstd * gv.y + bv.y;
            rr.z = (o[k].z - mu) * rstd * gv.z + bv.z;
            rr.w = (o[k].w - mu) * rstd * gv.w + bv.w;
            __builtin_nontemporal_store(rr, &orow[lane + 64 * k]);
        }
    }

    const float4* xf = (const float4*)(x + ((size_t)b * Tq + HALF + t0) * Dq);
#pragma unroll
    for (int r = 0; r < 4; ++r) {          // fresh second-half rows
        float4 o[4];
        float sum = 0.f, sq = 0.f;
#pragma unroll
        for (int k = 0; k < 4; ++k) {
            const float4 xv = xf[(size_t)r * 256 + lane + 64 * k];
            const float4 mv = mr[lane + 64 * k];
            o[k].x = xv.x + mv.x;
            o[k].y = xv.y + mv.y;
            o[k].z = xv.z + mv.z;
            o[k].w = xv.w + mv.w;
            sum += o[k].x + o[k].y + o[k].z + o[k].w;
            sq  += o[k].x * o[k].x + o[k].y * o[k].y + o[k].z * o[k].z + o[k].w * o[k].w;
        }
#pragma unroll
        for (int i = 32; i >= 1; i >>= 1) {
            sum += __shfl_xor(sum, i, 64);
            sq  += __shfl_xor(sq, i, 64);
        }
        const float mu   = sum * (1.0f / 1024.0f);
        const float var  = sq * (1.0f / 1024.0f) - mu * mu;
        const float rstd = rsqrtf(var + 1e-5f);
        f32x4* orow = (f32x4*)(out + ((size_t)b * Tq + HALF + t0 + r) * Dq);
#pragma unroll
        for (int k = 0; k < 4; ++k) {
            const float4 gv = gp[lane + 64 * k];
            const float4 bv = bp[lane + 64 * k];
            f32x4 rr;
            rr.x = (o[k].x - mu) * rstd * gv.x + bv.x;
            rr.y = (o[k].y - mu) * rstd * gv.y + bv.y;
            rr.z = (o[k].z - mu) * rstd * gv.z + bv.z;
            rr.w = (o[k].w - mu) * rstd * gv.w + bv.w;
            __builtin_nontemporal_store(rr, &orow[lane + 64 * k]);
        }
    }
}

// ---------------- fallback path (R3 structure, known-good 59.4 us) ----------------
__global__ __launch_bounds__(256) void k_leaf_partial(const float* __restrict__ x,
                                                      float* __restrict__ partial) {
    const int bl = blockIdx.x;
    const int p  = blockIdx.y;
    const int q  = threadIdx.x;
    const int b = bl >> 3, l = bl & 7;
    const float4* xp = (const float4*)(x + ((size_t)b * Tq + (size_t)l * SUBSEQ + (size_t)p * (SUBSEQ / TSPLIT)) * Dq) + q;
    float4 s = {0.f, 0.f, 0.f, 0.f};
#pragma unroll 8
    for (int t = 0; t < SUBSEQ / TSPLIT; ++t) {
        float4 xv = xp[(size_t)t * (Dq / 4)];
        s.x += xv.x; s.y += xv.y; s.z += xv.z; s.w += xv.w;
    }
    ((float4*)partial)[((size_t)bl * TSPLIT + p) * (Dq / 4) + q] = s;
}

__global__ __launch_bounds__(1024) void k_mixture(const float* __restrict__ partial,
                                                  const float* __restrict__ nw,
                                                  float* __restrict__ mixture) {
    const int b = blockIdx.x;
    const int d = threadIdx.x;
    float v[NNODES];
    float m = -1e30f;
#pragma unroll
    for (int n = 0; n < NNODES; ++n) {
        v[n] = nw[n * Dq + d];
        m = fmaxf(m, v[n]);
    }
    float denom = 0.f;
#pragma unroll
    for (int n = 0; n < NNODES; ++n) {
        v[n] = expf(v[n] - m);
        denom += v[n];
    }
    const float inv_denom = 1.0f / denom;
    float acc = 0.f;
#pragma unroll
    for (int l = 0; l < 8; ++l) {
        float s = 0.f;
#pragma unroll
        for (int p = 0; p < TSPLIT; ++p)
            s += partial[(((size_t)(b * 8 + l)) * TSPLIT + p) * Dq + d];
        acc += (v[7 + l] * inv_denom) * (s * (1.0f / (float)SUBSEQ));
    }
    mixture[b * Dq + d] = acc;
}

__global__ __launch_bounds__(256) void k_ln(const float* __restrict__ x,
                                            const float* __restrict__ mixture,
                                            const float* __restrict__ gamma,
                                            const float* __restrict__ beta,
                                            float* __restrict__ out) {
    const int wid  = threadIdx.x >> 6;
    const int lane = threadIdx.x & 63;
    const int row  = blockIdx.x * 4 + wid;
    const int b    = row >> 12;
    const float4* xr = (const float4*)(x + (size_t)row * Dq);
    const float4* mr = (const float4*)(mixture + (size_t)b * Dq);
    float4 o[4];
    float sum = 0.f, sq = 0.f;
#pragma unroll
    for (int k = 0; k < 4; ++k) {
        const float4 xv = xr[lane + 64 * k];
        const float4 mv = mr[lane + 64 * k];
        o[k].x = xv.x + mv.x;
        o[k].y = xv.y + mv.y;
        o[k].z = xv.z + mv.z;
        o[k].w = xv.w + mv.w;
        sum += o[k].x + o[k].y + o[k].z + o[k].w;
        sq  += o[k].x * o[k].x + o[k].y * o[k].y + o[k].z * o[k].z + o[k].w * o[k].w;
    }
#pragma unroll
    for (int i = 32; i >= 1; i >>= 1) {
        sum += __shfl_xor(sum, i, 64);
        sq  += __shfl_xor(sq, i, 64);
    }
    const float mu   = sum * (1.0f / 1024.0f);
    const float var  = sq * (1.0f / 1024.0f) - mu * mu;
    const float rstd = rsqrtf(var + 1e-5f);
    f32x4* orow = (f32x4*)(out + (size_t)row * Dq);
#pragma unroll
    for (int k = 0; k < 4; ++k) {
        const float4 gv = ((const float4*)gamma)[lane + 64 * k];
        const float4 bv = ((const float4*)beta)[lane + 64 * k];
        f32x4 r;
        r.x = (o[k].x - mu) * rstd * gv.x + bv.x;
        r.y = (o[k].y - mu) * rstd * gv.y + bv.y;
        r.z = (o[k].z - mu) * rstd * gv.z + bv.z;
        r.w = (o[k].w - mu) * rstd * gv.w + bv.w;
        __builtin_nontemporal_store(r, &orow[lane + 64 * k]);
    }
}

extern "C" void kernel_launch(void* const* d_in, const int* in_sizes, int n_in,
                              void* d_out, int out_size, void* d_ws, size_t ws_size,
                              hipStream_t stream) {
    const float* x     = (const float*)d_in[0];
    // d_in[1] = W_proj, d_in[2] = threshold: numerically dead (all gated states are exactly 0)
    const float* nw    = (const float*)d_in[3];
    const float* gamma = (const float*)d_in[4];
    const float* beta  = (const float*)d_in[5];
    float* out = (float*)d_out;

    float* partial = (float*)d_ws;                 // 512*1024 f32 = 2 MiB (both paths)
    float* mixture = partial + (size_t)CGRID * Dq; // 8*1024 f32

    // Deterministic host-side decision: cooperative only if the runtime
    // guarantees CGRID blocks co-resident (same answer every call).
    int dev = 0;
    hipGetDevice(&dev);
    int ncu = 0;
    hipDeviceGetAttribute(&ncu, hipDeviceAttributeMultiprocessorCount, dev);
    int nb = 0;
    hipError_t eq = hipOccupancyMaxActiveBlocksPerMultiprocessor(&nb, (const void*)k_fused, CBLOCK, 0);
    bool coop = (eq == hipSuccess) && ((long)nb * ncu >= CGRID);

    if (coop) {
        void* args[] = {(void*)&x, (void*)&nw, (void*)&gamma, (void*)&beta,
                        (void*)&partial, (void*)&mixture, (void*)&out};
        hipError_t el = hipLaunchCooperativeKernel((void*)k_fused, dim3(CGRID), dim3(CBLOCK),
                                                   args, 0, stream);
        if (el == hipSuccess) return;
        // fall through to non-cooperative path if launch refused
    }

    k_leaf_partial<<<dim3(Bq * 8, TSPLIT), 256, 0, stream>>>(x, partial);
    k_mixture<<<Bq, 1024, 0, stream>>>(partial, nw, mixture);
    k_ln<<<Bq * Tq / 4, 256, 0, stream>>>(x, mixture, gamma, beta, out);
}

// Round 9
// 56.966 us; speedup vs baseline: 1.0838x; 1.0428x over previous
//
#include <hip/hip_runtime.h>

#define Bq 8
#define Tq 4096
#define Dq 1024
#define NLEAF 8      // valid leaves (nodes 7..14)
#define SUBSEQ 256   // timesteps per leaf
#define TSPLIT 8     // partial splits per leaf (512 blocks total)
#define NNODES 15

typedef float f32x4 __attribute__((ext_vector_type(4)));

// Kernel 1: partial leaf sums. grid = (B*NLEAF, TSPLIT), block = 256 (float4 over D).
// (identical to R3)
__global__ __launch_bounds__(256) void k_leaf_partial(const float* __restrict__ x,
                                                      float* __restrict__ partial) {
    const int bl = blockIdx.x;          // b*8 + l
    const int p  = blockIdx.y;          // 0..7
    const int q  = threadIdx.x;         // float4 index over D (0..255)
    const int b = bl >> 3, l = bl & 7;
    const float4* xp = (const float4*)(x + ((size_t)b * Tq + (size_t)l * SUBSEQ + (size_t)p * (SUBSEQ / TSPLIT)) * Dq) + q;
    float4 s = {0.f, 0.f, 0.f, 0.f};
#pragma unroll 8
    for (int t = 0; t < SUBSEQ / TSPLIT; ++t) {
        float4 xv = xp[(size_t)t * (Dq / 4)];
        s.x += xv.x; s.y += xv.y; s.z += xv.z; s.w += xv.w;
    }
    ((float4*)partial)[((size_t)bl * TSPLIT + p) * (Dq / 4) + q] = s;
}

// Kernel 2: softmax over node_weights + mixture.
// RESHAPED vs R3: 32 blocks x 256 threads (was 8 x 1024) -> 4x more CUs
// hiding the L2 load latency; loads fully unrolled for ILP. Work identical.
__global__ __launch_bounds__(256) void k_mixture(const float* __restrict__ partial,
                                                 const float* __restrict__ nw,
                                                 float* __restrict__ mixture) {
    const int b = blockIdx.x >> 2;
    const int d = ((blockIdx.x & 3) << 8) + threadIdx.x;
    float v[NNODES];
    float m = -1e30f;
#pragma unroll
    for (int n = 0; n < NNODES; ++n) {
        v[n] = nw[n * Dq + d];
        m = fmaxf(m, v[n]);
    }
    float denom = 0.f;
#pragma unroll
    for (int n = 0; n < NNODES; ++n) {
        v[n] = expf(v[n] - m);
        denom += v[n];
    }
    const float inv_denom = 1.0f / denom;
    float acc = 0.f;
#pragma unroll
    for (int l = 0; l < NLEAF; ++l) {
        float s = 0.f;
#pragma unroll
        for (int p = 0; p < TSPLIT; ++p)
            s += partial[(((size_t)(b * NLEAF + l)) * TSPLIT + p) * Dq + d];
        acc += (v[7 + l] * inv_denom) * (s * (1.0f / (float)SUBSEQ));
    }
    mixture[b * Dq + d] = acc;
}

// Kernel 3: out[b,t,:] = LN(x[b,t,:] + mixture[b,:]) * gamma + beta.
// (identical to R3: wave-per-row, no LDS/barriers, NT stores)
__global__ __launch_bounds__(256) void k_ln(const float* __restrict__ x,
                                            const float* __restrict__ mixture,
                                            const float* __restrict__ gamma,
                                            const float* __restrict__ beta,
                                            float* __restrict__ out) {
    const int wid  = threadIdx.x >> 6;
    const int lane = threadIdx.x & 63;
    const int row  = blockIdx.x * 4 + wid;   // b*T + t
    const int b    = row >> 12;              // T = 4096
    const float4* xr = (const float4*)(x + (size_t)row * Dq);
    const float4* mr = (const float4*)(mixture + (size_t)b * Dq);
    float4 o[4];
    float sum = 0.f, sq = 0.f;
#pragma unroll
    for (int k = 0; k < 4; ++k) {
        const float4 xv = xr[lane + 64 * k];
        const float4 mv = mr[lane + 64 * k];
        o[k].x = xv.x + mv.x;
        o[k].y = xv.y + mv.y;
        o[k].z = xv.z + mv.z;
        o[k].w = xv.w + mv.w;
        sum += o[k].x + o[k].y + o[k].z + o[k].w;
        sq  += o[k].x * o[k].x + o[k].y * o[k].y + o[k].z * o[k].z + o[k].w * o[k].w;
    }
#pragma unroll
    for (int i = 32; i >= 1; i >>= 1) {
        sum += __shfl_xor(sum, i, 64);
        sq  += __shfl_xor(sq, i, 64);
    }
    const float mu   = sum * (1.0f / 1024.0f);
    const float var  = sq * (1.0f / 1024.0f) - mu * mu;
    const float rstd = rsqrtf(var + 1e-5f);
    f32x4* orow = (f32x4*)(out + (size_t)row * Dq);
#pragma unroll
    for (int k = 0; k < 4; ++k) {
        const float4 gv = ((const float4*)gamma)[lane + 64 * k];
        const float4 bv = ((const float4*)beta)[lane + 64 * k];
        f32x4 r;
        r.x = (o[k].x - mu) * rstd * gv.x + bv.x;
        r.y = (o[k].y - mu) * rstd * gv.y + bv.y;
        r.z = (o[k].z - mu) * rstd * gv.z + bv.z;
        r.w = (o[k].w - mu) * rstd * gv.w + bv.w;
        __builtin_nontemporal_store(r, &orow[lane + 64 * k]);
    }
}

extern "C" void kernel_launch(void* const* d_in, const int* in_sizes, int n_in,
                              void* d_out, int out_size, void* d_ws, size_t ws_size,
                              hipStream_t stream) {
    const float* x     = (const float*)d_in[0];
    // d_in[1] = W_proj, d_in[2] = threshold: numerically dead (all gated states are exactly 0)
    const float* nw    = (const float*)d_in[3];
    const float* gamma = (const float*)d_in[4];
    const float* beta  = (const float*)d_in[5];
    float* out = (float*)d_out;

    float* partial = (float*)d_ws;                               // 8*8*8*1024 floats = 2 MiB
    float* mixture = partial + (size_t)Bq * NLEAF * TSPLIT * Dq; // 8*1024 floats

    k_leaf_partial<<<dim3(Bq * NLEAF, TSPLIT), 256, 0, stream>>>(x, partial);
    k_mixture<<<32, 256, 0, stream>>>(partial, nw, mixture);
    k_ln<<<Bq * Tq / 4, 256, 0, stream>>>(x, mixture, gamma, beta, out);
}

// Round 10
// 56.053 us; speedup vs baseline: 1.1014x; 1.0163x over previous
//
#include <hip/hip_runtime.h>

#define Bq 8
#define Tq 4096
#define Dq 1024
#define NNODES 15

typedef float f32x4 __attribute__((ext_vector_type(4)));

// Kernel A: fused leaf-mean + softmax + mixture, (b, d-slice)-parallel.
// grid = 256 (b = blk>>5, 32-float d-slice = blk&31), block = 512 (8 waves).
// Each block owns the FULL reduction for its (b, d-slice): reads
// x[b, 0:2048, d0:d0+32] (256 KiB), accumulates 8 leaf sums in-register,
// reduces across lanes/waves, then softmax(nw)+mixture for its 32 d's.
__global__ __launch_bounds__(512) void k_leafmix(const float* __restrict__ x,
                                                 const float* __restrict__ nw,
                                                 float* __restrict__ mixture) {
    const int b     = blockIdx.x >> 5;
    const int slice = blockIdx.x & 31;
    const int d0    = slice * 32;
    const int t     = threadIdx.x;
    const int qd    = t & 7;      // float4 column within slice
    const int rg    = t >> 3;     // row group 0..63
    const int wv    = t >> 6;     // wave 0..7
    const int lane  = t & 63;

    // rows r = rg + 64*k, k=0..31; leaf(r) = k>>2 (exact: 64*(k&3)+rg < 256)
    const float4* xb = (const float4*)(x + (size_t)b * Tq * Dq + d0) + qd;
    float4 acc[8];
#pragma unroll
    for (int l = 0; l < 8; ++l) acc[l] = {0.f, 0.f, 0.f, 0.f};
#pragma unroll
    for (int l = 0; l < 8; ++l) {
#pragma unroll
        for (int j = 0; j < 4; ++j) {
            const int r = rg + 64 * (l * 4 + j);
            const float4 xv = xb[(size_t)r * (Dq / 4)];
            acc[l].x += xv.x; acc[l].y += xv.y;
            acc[l].z += xv.z; acc[l].w += xv.w;
        }
    }
    // in-wave reduction over rg lane-bits 3,4,5 (lanes sharing qd)
#pragma unroll
    for (int m = 8; m <= 32; m <<= 1) {
#pragma unroll
        for (int l = 0; l < 8; ++l) {
            acc[l].x += __shfl_xor(acc[l].x, m, 64);
            acc[l].y += __shfl_xor(acc[l].y, m, 64);
            acc[l].z += __shfl_xor(acc[l].z, m, 64);
            acc[l].w += __shfl_xor(acc[l].w, m, 64);
        }
    }
    // cross-wave reduction via LDS
    __shared__ float4 lds[8][8][8];   // [wave][qd][leaf]
    if (lane < 8) {                    // lane == qd representative
#pragma unroll
        for (int l = 0; l < 8; ++l) lds[wv][lane][l] = acc[l];
    }
    __syncthreads();
    __shared__ float lsum[8][8][4];   // [qd][leaf][comp]
    if (t < 64) {
        const int q2 = t >> 3, l2 = t & 7;
        float4 a = lds[0][q2][l2];
#pragma unroll
        for (int w = 1; w < 8; ++w) {
            a.x += lds[w][q2][l2].x; a.y += lds[w][q2][l2].y;
            a.z += lds[w][q2][l2].z; a.w += lds[w][q2][l2].w;
        }
        lsum[q2][l2][0] = a.x; lsum[q2][l2][1] = a.y;
        lsum[q2][l2][2] = a.z; lsum[q2][l2][3] = a.w;
    }
    __syncthreads();
    // softmax + mixture for this block's 32 d's (one scalar d per thread)
    if (t < 32) {
        const int q2 = t >> 2, c = t & 3;
        const int d  = d0 + q2 * 4 + c;
        float v[NNODES];
        float m = -1e30f;
#pragma unroll
        for (int n = 0; n < NNODES; ++n) {
            v[n] = nw[n * Dq + d];
            m = fmaxf(m, v[n]);
        }
        float denom = 0.f;
#pragma unroll
        for (int n = 0; n < NNODES; ++n) {
            v[n] = expf(v[n] - m);
            denom += v[n];
        }
        const float inv_denom = 1.0f / denom;
        float mix = 0.f;
#pragma unroll
        for (int l = 0; l < 8; ++l)
            mix += (v[7 + l] * inv_denom) * (lsum[q2][l][c] * (1.0f / 256.0f));
        mixture[b * Dq + d] = mix;
    }
}

// Kernel B: out[b,t,:] = LN(x[b,t,:] + mixture[b,:]) * gamma + beta.
// (byte-identical structure to R9: wave-per-row, no LDS/barriers, NT stores)
__global__ __launch_bounds__(256) void k_ln(const float* __restrict__ x,
                                            const float* __restrict__ mixture,
                                            const float* __restrict__ gamma,
                                            const float* __restrict__ beta,
                                            float* __restrict__ out) {
    const int wid  = threadIdx.x >> 6;
    const int lane = threadIdx.x & 63;
    const int row  = blockIdx.x * 4 + wid;   // b*T + t
    const int b    = row >> 12;              // T = 4096
    const float4* xr = (const float4*)(x + (size_t)row * Dq);
    const float4* mr = (const float4*)(mixture + (size_t)b * Dq);
    float4 o[4];
    float sum = 0.f, sq = 0.f;
#pragma unroll
    for (int k = 0; k < 4; ++k) {
        const float4 xv = xr[lane + 64 * k];
        const float4 mv = mr[lane + 64 * k];
        o[k].x = xv.x + mv.x;
        o[k].y = xv.y + mv.y;
        o[k].z = xv.z + mv.z;
        o[k].w = xv.w + mv.w;
        sum += o[k].x + o[k].y + o[k].z + o[k].w;
        sq  += o[k].x * o[k].x + o[k].y * o[k].y + o[k].z * o[k].z + o[k].w * o[k].w;
    }
#pragma unroll
    for (int i = 32; i >= 1; i >>= 1) {
        sum += __shfl_xor(sum, i, 64);
        sq  += __shfl_xor(sq, i, 64);
    }
    const float mu   = sum * (1.0f / 1024.0f);
    const float var  = sq * (1.0f / 1024.0f) - mu * mu;
    const float rstd = rsqrtf(var + 1e-5f);
    f32x4* orow = (f32x4*)(out + (size_t)row * Dq);
#pragma unroll
    for (int k = 0; k < 4; ++k) {
        const float4 gv = ((const float4*)gamma)[lane + 64 * k];
        const float4 bv = ((const float4*)beta)[lane + 64 * k];
        f32x4 r;
        r.x = (o[k].x - mu) * rstd * gv.x + bv.x;
        r.y = (o[k].y - mu) * rstd * gv.y + bv.y;
        r.z = (o[k].z - mu) * rstd * gv.z + bv.z;
        r.w = (o[k].w - mu) * rstd * gv.w + bv.w;
        __builtin_nontemporal_store(r, &orow[lane + 64 * k]);
    }
}

extern "C" void kernel_launch(void* const* d_in, const int* in_sizes, int n_in,
                              void* d_out, int out_size, void* d_ws, size_t ws_size,
                              hipStream_t stream) {
    const float* x     = (const float*)d_in[0];
    // d_in[1] = W_proj, d_in[2] = threshold: numerically dead (all gated states are exactly 0)
    const float* nw    = (const float*)d_in[3];
    const float* gamma = (const float*)d_in[4];
    const float* beta  = (const float*)d_in[5];
    float* out = (float*)d_out;

    float* mixture = (float*)d_ws;   // 8*1024 floats

    k_leafmix<<<Bq * 32, 512, 0, stream>>>(x, nw, mixture);
    k_ln<<<Bq * Tq / 4, 256, 0, stream>>>(x, mixture, gamma, beta, out);
}